// Round 3
// baseline (596.227 us; speedup 1.0000x reference)
//
#include <hip/hip_runtime.h>
#include <hip/hip_bf16.h>

typedef __attribute__((ext_vector_type(8))) short short8;   // 8 bf16 = 4 VGPRs
typedef __attribute__((ext_vector_type(4))) float float4v;  // 4 fp32 acc
typedef __hip_bfloat16 bf16;

#define MFMA16(a, b, c) __builtin_amdgcn_mfma_f32_16x16x32_bf16((a), (b), (c), 0, 0, 0)

static __device__ __forceinline__ short8 load8(const bf16* p) {
    return *reinterpret_cast<const short8*>(p);
}

static __device__ __forceinline__ short bf_bits(float x) {
    union { bf16 b; short u; } c; c.b = __float2bfloat16(x); return c.u;
}

// A-fragment loaders: 8 consecutive K-elements starting at p.
static __device__ __forceinline__ short8 loadA(const bf16* p) { return load8(p); }
static __device__ __forceinline__ short8 loadA(const float* p) {
    float4 v0 = *reinterpret_cast<const float4*>(p);
    float4 v1 = *reinterpret_cast<const float4*>(p + 4);
    short8 r;
    r[0] = bf_bits(v0.x); r[1] = bf_bits(v0.y);
    r[2] = bf_bits(v0.z); r[3] = bf_bits(v0.w);
    r[4] = bf_bits(v1.x); r[5] = bf_bits(v1.y);
    r[6] = bf_bits(v1.z); r[7] = bf_bits(v1.w);
    return r;
}

// ---------------------------------------------------------------------------
// Transpose + convert one 1024x1024 fp32 weight W[k][n] -> bf16 Wt[n][k].
// ---------------------------------------------------------------------------
__global__ __launch_bounds__(256) void transpose_w(
    const float* __restrict__ in, bf16* __restrict__ out)
{
    __shared__ bf16 tile[64][65];  // +1 pad breaks bank aliasing
    int tx = threadIdx.x;          // 0..63
    int ty = threadIdx.y;          // 0..3
    int bx = blockIdx.x * 64, by = blockIdx.y * 64;
    for (int i = ty; i < 64; i += 4)
        tile[i][tx] = __float2bfloat16(in[(size_t)(by + i) * 1024 + bx + tx]);
    __syncthreads();
    for (int i = ty; i < 64; i += 4)
        out[(size_t)(bx + i) * 1024 + by + tx] = tile[tx][i];
}

// ---------------------------------------------------------------------------
// C[4096,1024] = X[4096,1024] @ W + bias, W given transposed bf16 Wt[n][k].
// Block = 256 thr (4 waves). Block tile 128(M) x 64(N); each wave 32x64.
// MODE 0: out[((b*16+h)*2048+s)*64+dk]   ([B,H,S,Dk]  — q, k)         OutT=bf16
// MODE 1: out[((b*16+h)*64+dk)*2048+s]   ([B,H,Dk,S]  — v transposed) OutT=bf16
// MODE 2: out[m*1024+n]                  (final projection)           OutT=float
// ---------------------------------------------------------------------------
template <int MODE, typename AT, typename OutT>
__global__ __launch_bounds__(256) void gemm_bias(
    const AT* __restrict__ X, const bf16* __restrict__ Wt,
    const float* __restrict__ bias, OutT* __restrict__ out)
{
    int lane = threadIdx.x & 63;
    int warp = threadIdx.x >> 6;
    int l16 = lane & 15, quad = lane >> 4;
    int m_base = blockIdx.y * 128 + warp * 32;
    int n_base = blockIdx.x * 64;

    const AT* Xa = X + (size_t)(m_base + l16) * 1024 + quad * 8;   // rows m_base..+15
    const AT* Xb = Xa + (size_t)16 * 1024;                         // rows +16..+31
    const bf16* Wp = Wt + (size_t)(n_base + l16) * 1024 + quad * 8;

    float4v zero = {0.f, 0.f, 0.f, 0.f};
    float4v acc[2][4];
    #pragma unroll
    for (int rb = 0; rb < 2; ++rb)
        #pragma unroll
        for (int g = 0; g < 4; ++g) acc[rb][g] = zero;

    for (int kt = 0; kt < 1024; kt += 32) {
        short8 a0 = loadA(Xa + kt);
        short8 a1 = loadA(Xb + kt);
        #pragma unroll
        for (int g = 0; g < 4; ++g) {
            short8 bg = load8(Wp + (size_t)g * 16 * 1024 + kt);
            acc[0][g] = MFMA16(a0, bg, acc[0][g]);
            acc[1][g] = MFMA16(a1, bg, acc[1][g]);
        }
    }

    float bsv[4];
    #pragma unroll
    for (int g = 0; g < 4; ++g)
        bsv[g] = bias[n_base + g * 16 + l16];

    #pragma unroll
    for (int rb = 0; rb < 2; ++rb) {
        #pragma unroll
        for (int g = 0; g < 4; ++g) {
            int n = n_base + g * 16 + l16;
            #pragma unroll
            for (int r = 0; r < 4; ++r) {
                int m = m_base + rb * 16 + quad * 4 + r;
                float val = acc[rb][g][r] + bsv[g];
                size_t idx;
                if (MODE == 0) {
                    int b = m >> 11, s = m & 2047, h = n >> 6, dk = n & 63;
                    idx = (((size_t)(b * 16 + h) * 2048 + s) * 64 + dk);
                } else if (MODE == 1) {
                    int b = m >> 11, s = m & 2047, h = n >> 6, dk = n & 63;
                    idx = (((size_t)(b * 16 + h) * 64 + dk) * 2048 + s);
                } else {
                    idx = (size_t)m * 1024 + n;
                }
                if (MODE == 2) {
                    out[idx] = (OutT)val;
                } else {
                    out[idx] = (OutT)__float2bfloat16(val);
                }
            }
        }
    }
}

// ---------------------------------------------------------------------------
// Flash attention. One wave (block=64) per (b, h, 16-query tile).
// Q,K in [B*H, 2048, 64]; V transposed [B*H, 64, 2048]; mask int32 [B, 2048].
// Online softmax over 32-key steps. P round-trips through LDS (row stride 56
// elems = 112 B, multiple of 16 B so ds_read_b128 stays aligned).
// Output written bf16 to [B, S, H*64] so final projection is a plain GEMM.
// ---------------------------------------------------------------------------
__global__ __launch_bounds__(64) void attn_fused(
    const bf16* __restrict__ Qm, const bf16* __restrict__ Km,
    const bf16* __restrict__ Vt, const int* __restrict__ mask,
    bf16* __restrict__ Oout)
{
    __shared__ __align__(16) bf16 P[16 * 56];
    int wid = blockIdx.x;       // 0..4095
    int bh = wid >> 7;          // b*16+h
    int qt = wid & 127;         // query tile within (b,h)
    int b = bh >> 4, h = bh & 15;
    int lane = threadIdx.x & 63;
    int l16 = lane & 15, quad = lane >> 4;

    const bf16* Qb = Qm + ((size_t)bh * 2048 + (size_t)qt * 16) * 64;
    const bf16* Kb = Km + (size_t)bh * 2048 * 64;
    const bf16* Vb = Vt + (size_t)bh * 64 * 2048;
    const int* mb = mask + b * 2048;

    // Q A-fragments (fixed for the whole K loop): A[m=l16][k=quad*8+j]
    short8 aq0 = load8(Qb + l16 * 64 + quad * 8);        // d 0..31
    short8 aq1 = load8(Qb + l16 * 64 + 32 + quad * 8);   // d 32..63

    float m_run[4], l_run[4];
    float4v Oacc[4];
    float4v zero = {0.f, 0.f, 0.f, 0.f};
    #pragma unroll
    for (int r = 0; r < 4; ++r) { m_run[r] = -INFINITY; l_run[r] = 0.f; }
    #pragma unroll
    for (int g = 0; g < 4; ++g) Oacc[g] = zero;

    for (int kt = 0; kt < 2048; kt += 32) {
        // --- S = Q K^T for 32 keys (two 16-col MFMA tiles) ---
        const bf16* K0 = Kb + (size_t)(kt + l16) * 64 + quad * 8;
        const bf16* K1 = K0 + 16 * 64;
        short8 bk0a = load8(K0);
        short8 bk0b = load8(K0 + 32);
        short8 bk1a = load8(K1);
        short8 bk1b = load8(K1 + 32);
        float4v S0 = zero, S1 = zero;
        S0 = MFMA16(aq0, bk0a, S0);
        S0 = MFMA16(aq1, bk0b, S0);
        S1 = MFMA16(aq0, bk1a, S1);
        S1 = MFMA16(aq1, bk1b, S1);

        // --- scale + mask (mask applied to scaled scores, like the ref) ---
        int mv0 = mb[kt + l16];
        int mv1 = mb[kt + 16 + l16];
        float s0[4], s1[4], pm[4];
        #pragma unroll
        for (int r = 0; r < 4; ++r) {
            s0[r] = (mv0 == 0) ? -1e9f : S0[r] * 0.125f;
            s1[r] = (mv1 == 0) ? -1e9f : S1[r] * 0.125f;
            pm[r] = fmaxf(s0[r], s1[r]);
        }
        // --- row max across the 16 lanes holding this row's columns ---
        #pragma unroll
        for (int off = 1; off <= 8; off <<= 1) {
            #pragma unroll
            for (int r = 0; r < 4; ++r)
                pm[r] = fmaxf(pm[r], __shfl_xor(pm[r], off, 64));
        }
        // --- online softmax update ---
        float alpha[4], p0[4], p1[4], rs[4];
        #pragma unroll
        for (int r = 0; r < 4; ++r) {
            float mn = fmaxf(m_run[r], pm[r]);
            alpha[r] = __expf(m_run[r] - mn);
            m_run[r] = mn;
            p0[r] = __expf(s0[r] - mn);
            p1[r] = __expf(s1[r] - mn);
            rs[r] = p0[r] + p1[r];
        }
        #pragma unroll
        for (int off = 1; off <= 8; off <<= 1) {
            #pragma unroll
            for (int r = 0; r < 4; ++r)
                rs[r] += __shfl_xor(rs[r], off, 64);
        }
        #pragma unroll
        for (int r = 0; r < 4; ++r)
            l_run[r] = l_run[r] * alpha[r] + rs[r];
        #pragma unroll
        for (int g = 0; g < 4; ++g)
            #pragma unroll
            for (int r = 0; r < 4; ++r)
                Oacc[g][r] *= alpha[r];

        // --- P (C-layout) -> LDS -> A-layout for PV ---
        __syncthreads();  // prior iteration's P reads done before overwrite
        #pragma unroll
        for (int r = 0; r < 4; ++r) {
            P[(quad * 4 + r) * 56 + l16]      = __float2bfloat16(p0[r]);
            P[(quad * 4 + r) * 56 + 16 + l16] = __float2bfloat16(p1[r]);
        }
        __syncthreads();
        short8 ap = load8(&P[l16 * 56 + quad * 8]);   // A[m=l16][k=quad*8+j]

        // --- O += P V : B[k=key][n=feat] = Vt[feat][key] contiguous ---
        #pragma unroll
        for (int g = 0; g < 4; ++g) {
            short8 bv = load8(Vb + (size_t)(g * 16 + l16) * 2048 + kt + quad * 8);
            Oacc[g] = MFMA16(ap, bv, Oacc[g]);
        }
    }

    // --- epilogue: O / l, write bf16 [B, S, H*64] ---
    #pragma unroll
    for (int r = 0; r < 4; ++r) {
        float inv = 1.f / l_run[r];
        int srow = qt * 16 + quad * 4 + r;
        size_t base = ((size_t)b * 2048 + srow) * 1024 + h * 64;
        #pragma unroll
        for (int g = 0; g < 4; ++g)
            Oout[base + g * 16 + l16] = __float2bfloat16(Oacc[g][r] * inv);
    }
}

// ---------------------------------------------------------------------------
// Workspace budget: EXACTLY 16 MB of d_ws (we previously used 40 MB and
// corrupted harness memory past d_ws+ws_size — first call passed, all
// restores thereafter were from clobbered pristine copies).
//   ws[ 0.. 8 MB): vb [B,H,Dk,S] during attention; then Wt(Wo) (2 MB)
//   ws[ 8..16 MB): Wt slot (2 MB, per-projection); then attn-out [B,S,1024] bf16
//   d_out[ 0.. 8 MB): qb [B,H,S,Dk] bf16   (dead before final GEMM writes)
//   d_out[ 8..16 MB): kb [B,H,S,Dk] bf16   (dead before final GEMM writes)
// Stream order serializes every reuse.
// ---------------------------------------------------------------------------
extern "C" void kernel_launch(void* const* d_in, const int* in_sizes, int n_in,
                              void* d_out, int out_size, void* d_ws, size_t ws_size,
                              hipStream_t stream) {
    const float* query = (const float*)d_in[0];
    const float* key   = (const float*)d_in[1];
    const float* value = (const float*)d_in[2];
    const int*   mask  = (const int*)d_in[3];
    const float* Wq = (const float*)d_in[4];
    const float* bq = (const float*)d_in[5];
    const float* Wk = (const float*)d_in[6];
    const float* bk = (const float*)d_in[7];
    const float* Wv = (const float*)d_in[8];
    const float* bv = (const float*)d_in[9];
    const float* Wo = (const float*)d_in[10];
    const float* bo = (const float*)d_in[11];

    char* ws = (char*)d_ws;
    const size_t MB = 1024 * 1024;
    bf16* vb   = (bf16*)ws;               // [B,H,Dk,S] 8 MB
    bf16* WtS  = (bf16*)(ws + 8 * MB);    // 2 MB rotating weight slot
    bf16* aout = (bf16*)(ws + 8 * MB);    // attn out [B,S,1024] 8 MB (after WtS dead)
    bf16* WtO  = (bf16*)ws;               // Wo^T 2 MB (after vb dead)
    bf16* qb   = (bf16*)d_out;            // 8 MB scratch in d_out
    bf16* kb   = (bf16*)((char*)d_out + 8 * MB);
    float* out = (float*)d_out;

    dim3 tgrid(16, 16), tblk(64, 4), ggrid(16, 32);

    transpose_w<<<tgrid, tblk, 0, stream>>>(Wq, WtS);
    gemm_bias<0, float, bf16><<<ggrid, 256, 0, stream>>>(query, WtS, bq, qb);

    transpose_w<<<tgrid, tblk, 0, stream>>>(Wk, WtS);
    gemm_bias<0, float, bf16><<<ggrid, 256, 0, stream>>>(key, WtS, bk, kb);

    transpose_w<<<tgrid, tblk, 0, stream>>>(Wv, WtS);
    gemm_bias<1, float, bf16><<<ggrid, 256, 0, stream>>>(value, WtS, bv, vb);

    attn_fused<<<dim3(4096), dim3(64), 0, stream>>>(qb, kb, vb, mask, aout);

    transpose_w<<<tgrid, tblk, 0, stream>>>(Wo, WtO);
    gemm_bias<2, bf16, float><<<ggrid, 256, 0, stream>>>(aout, WtO, bo, out);
}